// Round 7
// baseline (1547.168 us; speedup 1.0000x reference)
//
#include <hip/hip_runtime.h>
#include <cstdint>
#include <cstddef>

#define EDIM  512
#define NROWS 16384
#define NE    8192
#define XQSZ  (NROWS * EDIM)   // 8388608
#define NTILE 64               // 8192 codes / 128 per tile

// workspace byte offsets
#define OFF_PART  0                          // 2048 doubles = 16384 B
#define OFF_Z     16384                      // NROWS*4 = 65536
#define OFF_C2    81920                      // NE*4 = 32768
#define OFF_KEYS  114688                     // NROWS*8 = 131072
#define OFF_TMIN  245760                     // NROWS*NTILE*4 = 4 MB
#define OFF_CNT   4440064                    // 256 B (padded)
#define OFF_LIST  4441088                    // NROWS*NTILE*4 = 4 MB
#define OFF_XH    8635392                    // 16 MB
#define OFF_WH    25412608                   // 8 MB  (end ~34 MB < ws)

typedef __attribute__((ext_vector_type(8)))  short          short8;
typedef __attribute__((ext_vector_type(16))) float          f32x16;
typedef __attribute__((ext_vector_type(4)))  unsigned short u16x4;

// ---------------- rownorm (numpy pairwise order) ----------------
__global__ void k_rownorm(const float* __restrict__ in, float* __restrict__ out, int nrows) {
#pragma clang fp contract(off)
    int row = blockIdx.x * blockDim.x + threadIdx.x;
    if (row >= nrows) return;
    const float* p = in + (size_t)row * EDIM;
    float S[4];
#pragma unroll
    for (int b = 0; b < 4; ++b) {
        const float* q = p + b * 128;
        float r[8];
#pragma unroll
        for (int j = 0; j < 8; ++j) { float v = q[j]; r[j] = v * v; }
        for (int i = 8; i < 128; i += 8) {
#pragma unroll
            for (int j = 0; j < 8; ++j) { float v = q[i + j]; r[j] = r[j] + v * v; }
        }
        S[b] = ((r[0] + r[1]) + (r[2] + r[3])) + ((r[4] + r[5]) + (r[6] + r[7]));
    }
    out[row] = (S[0] + S[1]) + (S[2] + S[3]);
}

// ---------------- hi-bf16 conversion ----------------
__device__ __forceinline__ unsigned short f2bf(float f) {
    unsigned u = __float_as_uint(f);
    return (unsigned short)((u + 0x7FFFu + ((u >> 16) & 1u)) >> 16);
}

__global__ __launch_bounds__(256) void k_split_hi(const float* __restrict__ in,
        unsigned short* __restrict__ outp, int n8) {
    int i = blockIdx.x * 256 + threadIdx.x;
    if (i >= n8) return;
    const float* p = in + (size_t)i * 8;
    float4 a = *(const float4*)p, b = *(const float4*)(p + 4);
    u16x4 h0, h1;
    h0[0]=f2bf(a.x); h0[1]=f2bf(a.y); h0[2]=f2bf(a.z); h0[3]=f2bf(a.w);
    h1[0]=f2bf(b.x); h1[1]=f2bf(b.y); h1[2]=f2bf(b.z); h1[3]=f2bf(b.w);
    unsigned short* o = outp + (size_t)i * 8;
    *(u16x4*)o = h0; *(u16x4*)(o + 4) = h1;
}

// ---------------- pass A: hi-GEMM, per-(row,tile) approx-min ----------------
__device__ __forceinline__ void gld16(const void* g, void* l) {
    __builtin_amdgcn_global_load_lds((const __attribute__((address_space(1))) void*)g,
                                     (__attribute__((address_space(3))) void*)l, 16, 0, 0);
}

#define GBM 128
#define GBN 128
#define GBK 64

__global__ __launch_bounds__(256) void k_argmin_hi(
        const unsigned short* __restrict__ Xh, const unsigned short* __restrict__ Wh,
        const float* __restrict__ c2, unsigned* __restrict__ tmin) {
    __shared__ __align__(16) unsigned short At[GBM * GBK];
    __shared__ __align__(16) unsigned short Bt[GBN * GBK];
    __shared__ unsigned smin[GBM];

    const int tid = threadIdx.x;
    const int lane = tid & 63, wid = tid >> 6;
    const int wr = wid >> 1, wc = wid & 1;

    const int bid = blockIdx.x;
    const int swz = (bid & 7) * 1024 + (bid >> 3);   // 8192 % 8 == 0, bijective
    const int rowtile = swz & 127, codetile = swz >> 7;
    const int row0 = rowtile * GBM, code0 = codetile * GBN;

    if (tid < GBM) smin[tid] = 0xFFFFFFFFu;

    f32x16 acc[2][2];
#pragma unroll
    for (int i = 0; i < 2; ++i)
#pragma unroll
        for (int j = 0; j < 2; ++j)
#pragma unroll
            for (int r = 0; r < 16; ++r) acc[i][j][r] = 0.0f;

    size_t ga[4], gb[4];
#pragma unroll
    for (int i = 0; i < 4; ++i) {
        int chunk = i * 256 + tid;
        int row   = chunk >> 3;
        int kcs   = (chunk & 7) ^ (row & 7);
        ga[i] = (size_t)(row0 + row) * EDIM + kcs * 8;
        gb[i] = (size_t)(code0 + row) * EDIM + kcs * 8;
    }

    const int ra0 = wr * 64 + (lane & 31);
    const int rb0 = wc * 64 + (lane & 31);
    const int kh  = lane >> 5;
    const int sa  = ra0 & 7, sb = rb0 & 7;

    for (int kt = 0; kt < EDIM / GBK; ++kt) {
        const size_t ko = (size_t)kt * GBK;
#pragma unroll
        for (int i = 0; i < 4; ++i) {
            gld16(Xh + ga[i] + ko, (char*)At + i * 4096 + wid * 1024);
            gld16(Wh + gb[i] + ko, (char*)Bt + i * 4096 + wid * 1024);
        }
        __syncthreads();
#pragma unroll
        for (int ks = 0; ks < 4; ++ks) {
            const int ch = ks * 2 + kh;
            short8 a0 = *(const short8*)((const char*)At + ra0 * 128        + ((ch ^ sa) * 16));
            short8 a1 = *(const short8*)((const char*)At + (ra0 + 32) * 128 + ((ch ^ sa) * 16));
            short8 b0 = *(const short8*)((const char*)Bt + rb0 * 128        + ((ch ^ sb) * 16));
            short8 b1 = *(const short8*)((const char*)Bt + (rb0 + 32) * 128 + ((ch ^ sb) * 16));
            acc[0][0] = __builtin_amdgcn_mfma_f32_32x32x16_bf16(a0, b0, acc[0][0], 0, 0, 0);
            acc[0][1] = __builtin_amdgcn_mfma_f32_32x32x16_bf16(a0, b1, acc[0][1], 0, 0, 0);
            acc[1][0] = __builtin_amdgcn_mfma_f32_32x32x16_bf16(a1, b0, acc[1][0], 0, 0, 0);
            acc[1][1] = __builtin_amdgcn_mfma_f32_32x32x16_bf16(a1, b1, acc[1][1], 0, 0, 0);
        }
        __syncthreads();
    }

    // approx d (shifted +4 to stay positive): d~ = 4 + c2 - 2*m_hi
    const int j0 = code0 + wc * 64 + (lane & 31);
    const float c20 = c2[j0], c21 = c2[j0 + 32];
#pragma unroll
    for (int mi = 0; mi < 2; ++mi) {
#pragma unroll
        for (int reg = 0; reg < 16; ++reg) {
            const int rl = wr * 64 + mi * 32 + (reg & 3) + 8 * (reg >> 2) + 4 * kh;
            const float d0 = (4.0f + c20) - 2.0f * acc[mi][0][reg];
            const float d1 = (4.0f + c21) - 2.0f * acc[mi][1][reg];
            unsigned u0 = __float_as_uint(d0), u1 = __float_as_uint(d1);
            unsigned u = u0 < u1 ? u0 : u1;
#pragma unroll
            for (int m = 1; m <= 16; m <<= 1) {
                unsigned o = __shfl_xor(u, m, 64);
                if (o < u) u = o;
            }
            if ((lane & 31) == 0) atomicMin(&smin[rl], u);
        }
    }
    __syncthreads();
    if (tid < GBM) tmin[codetile * NROWS + row0 + tid] = smin[tid];
}

// ---------------- pass B: per-row candidate tile selection ----------------
// Rigorous: for j* (true argmin) to qualify need thr >= mn + 2E where
// E <= 2*(2^-8+2^-8+2^-16)*||x||*||w||max <= 4.35e-5*sqrt(Z) (itself 2x
// conservative vs the 2^-9 half-ulp bound); + f32 tie/rounding window.
__global__ __launch_bounds__(256) void k_select(
        const unsigned* __restrict__ tmin, const float* __restrict__ Z,
        int* __restrict__ cnt, int* __restrict__ list) {
    const int row = blockIdx.x * 256 + threadIdx.x;
    unsigned mn = 0xFFFFFFFFu;
    for (int t = 0; t < NTILE; ++t) {
        unsigned v = tmin[t * NROWS + row];
        if (v < mn) mn = v;
    }
    const float margin = 8.7e-5f * sqrtf(Z[row]) + 1.7e-4f;   // 2E + tie window
    const float thr = __uint_as_float(mn) + margin;
    for (int t = 0; t < NTILE; ++t) {
        if (__uint_as_float(tmin[t * NROWS + row]) <= thr) {
            int p = atomicAdd(&cnt[t], 1);
            list[t * NROWS + p] = row;
        }
    }
}

// ---------------- pass C: exact rescore (vectorized) ----------------
// grid (NTILE*4, 4). Block: 256 thr = 32 codes x 8 rows. Wl: 32 codes x 512
// f32 with float4-chunk XOR swizzle (phys word = c*512 + (d ^ ((c&7)<<2)))
// -> 64 KB; Xl: 8 rows x 512 f32 (16 KB); total exactly 80 KB = 2 blocks/CU.
// Inner: float4 LDS reads (W 4-way = b128 bandwidth floor; X broadcast),
// 8 independent accumulators, pairwise-combined. d via (Z+c2)-2m in f32,
// packed key with first-index tiebreak -> deterministic.
__global__ __launch_bounds__(256) void k_rescore(
        const float* __restrict__ x, const float* __restrict__ W,
        const float* __restrict__ Z, const float* __restrict__ c2,
        const int* __restrict__ cnt, const int* __restrict__ list,
        unsigned long long* __restrict__ keys) {
    __shared__ float Wl[32 * 512];   // 64 KB
    __shared__ float Xl[8 * 512];    // 16 KB

    const int tile = blockIdx.x >> 2, q = blockIdx.x & 3;
    const int n = cnt[tile];
    if (n == 0) return;
    const int* rows = list + tile * NROWS;
    const int tid = threadIdx.x;
    const int c = tid & 31, rs = tid >> 5;
    const int jbase = tile * 128 + q * 32;

    // stage Wl (swizzled). i indexes float4 chunks: 32 codes * 128 chunks.
    for (int i = tid; i < 32 * 128; i += 256) {
        int cc = i >> 7, ch = i & 127;
        float4 v = *(const float4*)(W + (size_t)(jbase + cc) * 512 + ch * 4);
        *(float4*)&Wl[cc * 512 + ((ch * 4) ^ ((cc & 7) << 2))] = v;
    }
    const float c2j = c2[jbase + c];
    const int k4 = (c & 7) << 2;
    const float* wr = Wl + c * 512;
    const float* xr = Xl + rs * 512;
    __syncthreads();

    for (int chk = (int)blockIdx.y; chk * 8 < n; chk += 4) {
        __syncthreads();   // previous compute done before Xl overwrite
        {
            const int rr = chk * 8 + rs;
            if (rr < n) {
                const float* xp = x + (size_t)rows[rr] * 512;
                float* xl = Xl + rs * 512;
                const int d0 = c * 4;
#pragma unroll
                for (int v = 0; v < 4; ++v)
                    *(float4*)(xl + d0 + v * 128) = *(const float4*)(xp + d0 + v * 128);
            }
        }
        __syncthreads();

        float4 s0 = {0.f,0.f,0.f,0.f}, s1 = {0.f,0.f,0.f,0.f};
#pragma unroll 8
        for (int d = 0; d < 512; d += 8) {
            float4 xa = *(const float4*)(xr + d);
            float4 xb = *(const float4*)(xr + d + 4);
            float4 wa = *(const float4*)(wr + (d ^ k4));
            float4 wb = *(const float4*)(wr + ((d + 4) ^ k4));
            s0.x = fmaf(xa.x, wa.x, s0.x); s0.y = fmaf(xa.y, wa.y, s0.y);
            s0.z = fmaf(xa.z, wa.z, s0.z); s0.w = fmaf(xa.w, wa.w, s0.w);
            s1.x = fmaf(xb.x, wb.x, s1.x); s1.y = fmaf(xb.y, wb.y, s1.y);
            s1.z = fmaf(xb.z, wb.z, s1.z); s1.w = fmaf(xb.w, wb.w, s1.w);
        }
        const float m = ((s0.x + s0.y) + (s0.z + s0.w)) + ((s1.x + s1.y) + (s1.z + s1.w));

        unsigned long long k = ~0ull;
        int r = 0;
        const int ri = chk * 8 + rs;
        if (ri < n) {
            r = rows[ri];
            const float dd = (Z[r] + c2j) - 2.0f * m;
            k = (((unsigned long long)__float_as_uint(dd)) << 13) | (unsigned)(jbase + c);
        }
#pragma unroll
        for (int mm = 1; mm <= 16; mm <<= 1) {
            unsigned long long o = __shfl_xor(k, mm, 64);
            if (o < k) k = o;
        }
        if (c == 0 && ri < n) atomicMin(&keys[r], k);
    }
}

// ---------------- gather / loss partials / finalize ----------------
__global__ __launch_bounds__(256) void k_gather(
        const float* __restrict__ x, const float* __restrict__ W,
        const unsigned long long* __restrict__ keys,
        float* __restrict__ out, double* __restrict__ part) {
    const int tid = threadIdx.x;
    const int row = blockIdx.x * 8 + (tid >> 5);
    const int c = tid & 31;
    const int idx = (int)(keys[row] & 0x1FFFull);

    const float* wrow = W + (size_t)idx * EDIM;
    const float* xrow = x + (size_t)row * EDIM;
    float* orow = out + (size_t)row * EDIM;

    double lsum = 0.0;
#pragma unroll
    for (int v = 0; v < 4; ++v) {
        const int d = c * 4 + v * 128;
        float4 xv = *(const float4*)(xrow + d);
        float4 wv = *(const float4*)(wrow + d);
        float t0 = wv.x - xv.x, t1 = wv.y - xv.y, t2 = wv.z - xv.z, t3 = wv.w - xv.w;
        float4 ov = { xv.x + t0, xv.y + t1, xv.z + t2, xv.w + t3 };
        *(float4*)(orow + d) = ov;
        lsum += (double)t0 * t0 + (double)t1 * t1 + (double)t2 * t2 + (double)t3 * t3;
    }
    if (c == 0) out[XQSZ + 1 + row] = (float)idx;

#pragma unroll
    for (int off = 32; off > 0; off >>= 1) lsum += __shfl_down(lsum, off, 64);
    __shared__ double pb[4];
    if ((tid & 63) == 0) pb[tid >> 6] = lsum;
    __syncthreads();
    if (tid == 0) part[blockIdx.x] = pb[0] + pb[1] + pb[2] + pb[3];
}

__global__ __launch_bounds__(256) void k_finalize(float* __restrict__ out,
        const double* __restrict__ part) {
    const int tid = threadIdx.x;
    double s = 0.0;
    for (int i = tid; i < 2048; i += 256) s += part[i];
#pragma unroll
    for (int off = 32; off > 0; off >>= 1) s += __shfl_down(s, off, 64);
    __shared__ double pb[4];
    if ((tid & 63) == 0) pb[tid >> 6] = s;
    __syncthreads();
    if (tid == 0) out[XQSZ] = (float)(0.25 * (pb[0] + pb[1] + pb[2] + pb[3]) / (double)XQSZ);
}

extern "C" void kernel_launch(void* const* d_in, const int* in_sizes, int n_in,
                              void* d_out, int out_size, void* d_ws, size_t ws_size,
                              hipStream_t stream) {
    const float* x = (const float*)d_in[0];
    const float* W = (const float*)d_in[3];
    float* out = (float*)d_out;
    char* ws = (char*)d_ws;

    double* part = (double*)(ws + OFF_PART);
    float* Z    = (float*)(ws + OFF_Z);
    float* c2   = (float*)(ws + OFF_C2);
    unsigned long long* keys = (unsigned long long*)(ws + OFF_KEYS);
    unsigned* tmin = (unsigned*)(ws + OFF_TMIN);
    int* cnt  = (int*)(ws + OFF_CNT);
    int* list = (int*)(ws + OFF_LIST);
    unsigned short* Xh = (unsigned short*)(ws + OFF_XH);
    unsigned short* Wh = (unsigned short*)(ws + OFF_WH);

    hipMemsetAsync(keys, 0xFF, NROWS * sizeof(unsigned long long), stream);
    hipMemsetAsync(cnt, 0, NTILE * sizeof(int), stream);
    k_rownorm<<<NROWS / 256, 256, 0, stream>>>(x, Z, NROWS);
    k_rownorm<<<NE / 256, 256, 0, stream>>>(W, c2, NE);
    k_split_hi<<<(NROWS * EDIM / 8) / 256, 256, 0, stream>>>(x, Xh, NROWS * EDIM / 8);
    k_split_hi<<<(NE * EDIM / 8) / 256, 256, 0, stream>>>(W, Wh, NE * EDIM / 8);
    k_argmin_hi<<<(NROWS / GBM) * (NE / GBN), 256, 0, stream>>>(Xh, Wh, c2, tmin);
    k_select<<<NROWS / 256, 256, 0, stream>>>(tmin, Z, cnt, list);
    k_rescore<<<dim3(NTILE * 4, 4), 256, 0, stream>>>(x, W, Z, c2, cnt, list, keys);
    k_gather<<<NROWS / 8, 256, 0, stream>>>(x, W, keys, out, part);
    k_finalize<<<1, 256, 0, stream>>>(out, part);
}

// Round 8
// 679.647 us; speedup vs baseline: 2.2764x; 2.2764x over previous
//
#include <hip/hip_runtime.h>
#include <cstdint>
#include <cstddef>

#define EDIM  512
#define NROWS 16384
#define NE    8192
#define XQSZ  (NROWS * EDIM)   // 8388608
#define NTILE 64               // 8192 codes / 128 per tile
#define K3    1536             // 3-block split: [hi, mid, lo]

// workspace byte offsets
#define OFF_PART  0                          // 2048 doubles
#define OFF_Z     16384
#define OFF_C2    81920
#define OFF_KEYS  114688
#define OFF_TMIN  245760                     // NROWS*NTILE*4 = 4 MB
#define OFF_CNT   4440064
#define OFF_LIST  4441088                    // NROWS*NTILE*4 = 4 MB
#define OFF_XE    8635392                    // NROWS*K3*2 = 48 MB
#define OFF_WE    58967040                   // NE*K3*2 = 24 MB (end ~84 MB)

typedef __attribute__((ext_vector_type(8)))  short          short8;
typedef __attribute__((ext_vector_type(16))) float          f32x16;
typedef __attribute__((ext_vector_type(4)))  unsigned short u16x4;

// ---------------- rownorm (numpy pairwise order) ----------------
__global__ void k_rownorm(const float* __restrict__ in, float* __restrict__ out, int nrows) {
#pragma clang fp contract(off)
    int row = blockIdx.x * blockDim.x + threadIdx.x;
    if (row >= nrows) return;
    const float* p = in + (size_t)row * EDIM;
    float S[4];
#pragma unroll
    for (int b = 0; b < 4; ++b) {
        const float* q = p + b * 128;
        float r[8];
#pragma unroll
        for (int j = 0; j < 8; ++j) { float v = q[j]; r[j] = v * v; }
        for (int i = 8; i < 128; i += 8) {
#pragma unroll
            for (int j = 0; j < 8; ++j) { float v = q[i + j]; r[j] = r[j] + v * v; }
        }
        S[b] = ((r[0] + r[1]) + (r[2] + r[3])) + ((r[4] + r[5]) + (r[6] + r[7]));
    }
    out[row] = (S[0] + S[1]) + (S[2] + S[3]);
}

// ---------------- bf16 3-way split [hi, mid, lo], exact ----------------
__device__ __forceinline__ unsigned short f2bf(float f) {
    unsigned u = __float_as_uint(f);
    return (unsigned short)((u + 0x7FFFu + ((u >> 16) & 1u)) >> 16);
}
__device__ __forceinline__ float bf2f(unsigned short h) {
    return __uint_as_float(((unsigned)h) << 16);
}

__global__ __launch_bounds__(256) void k_split3(const float* __restrict__ in,
        unsigned short* __restrict__ outp, int nrows) {
    int e = blockIdx.x * 256 + threadIdx.x;
    int row = e >> 7;               // 128 float4-groups per row
    int d0  = (e & 127) << 2;
    if (row >= nrows) return;
    float4 v = *(const float4*)(in + (size_t)row * EDIM + d0);
    float vv[4] = {v.x, v.y, v.z, v.w};
    u16x4 H, M, L;
#pragma unroll
    for (int i = 0; i < 4; ++i) {
        float f = vv[i];
        unsigned short h = f2bf(f);
        float r1 = f - bf2f(h);          // exact
        unsigned short m = f2bf(r1);
        float r2 = r1 - bf2f(m);         // exact
        L[i] = f2bf(r2); H[i] = h; M[i] = m;
    }
    unsigned short* o = outp + (size_t)row * K3 + d0;
    *(u16x4*)(o) = H; *(u16x4*)(o + EDIM) = M; *(u16x4*)(o + 2 * EDIM) = L;
}

// ---------------- shared MFMA helpers ----------------
__device__ __forceinline__ void gld16(const void* g, void* l) {
    __builtin_amdgcn_global_load_lds((const __attribute__((address_space(1))) void*)g,
                                     (__attribute__((address_space(3))) void*)l, 16, 0, 0);
}

#define GBM 128
#define GBN 128
#define GBK 64

// ---------------- pass A: hi-GEMM (block 0 of Xe/We), per-(row,tile) min ----
__global__ __launch_bounds__(256) void k_argmin_hi(
        const unsigned short* __restrict__ Xe, const unsigned short* __restrict__ We,
        const float* __restrict__ c2, unsigned* __restrict__ tmin) {
    __shared__ __align__(16) unsigned short At[GBM * GBK];
    __shared__ __align__(16) unsigned short Bt[GBN * GBK];
    __shared__ unsigned smin[GBM];

    const int tid = threadIdx.x;
    const int lane = tid & 63, wid = tid >> 6;
    const int wr = wid >> 1, wc = wid & 1;

    const int bid = blockIdx.x;
    const int swz = (bid & 7) * 1024 + (bid >> 3);   // 8192 % 8 == 0, bijective
    const int rowtile = swz & 127, codetile = swz >> 7;
    const int row0 = rowtile * GBM, code0 = codetile * GBN;

    if (tid < GBM) smin[tid] = 0xFFFFFFFFu;

    f32x16 acc[2][2];
#pragma unroll
    for (int i = 0; i < 2; ++i)
#pragma unroll
        for (int j = 0; j < 2; ++j)
#pragma unroll
            for (int r = 0; r < 16; ++r) acc[i][j][r] = 0.0f;

    size_t ga[4], gb[4];
#pragma unroll
    for (int i = 0; i < 4; ++i) {
        int chunk = i * 256 + tid;
        int row   = chunk >> 3;
        int kcs   = (chunk & 7) ^ (row & 7);
        ga[i] = (size_t)(row0 + row) * K3 + kcs * 8;
        gb[i] = (size_t)(code0 + row) * K3 + kcs * 8;
    }

    const int ra0 = wr * 64 + (lane & 31);
    const int rb0 = wc * 64 + (lane & 31);
    const int kh  = lane >> 5;
    const int sa  = ra0 & 7, sb = rb0 & 7;

    for (int kt = 0; kt < EDIM / GBK; ++kt) {
        const size_t ko = (size_t)kt * GBK;
#pragma unroll
        for (int i = 0; i < 4; ++i) {
            gld16(Xe + ga[i] + ko, (char*)At + i * 4096 + wid * 1024);
            gld16(We + gb[i] + ko, (char*)Bt + i * 4096 + wid * 1024);
        }
        __syncthreads();
#pragma unroll
        for (int ks = 0; ks < 4; ++ks) {
            const int ch = ks * 2 + kh;
            short8 a0 = *(const short8*)((const char*)At + ra0 * 128        + ((ch ^ sa) * 16));
            short8 a1 = *(const short8*)((const char*)At + (ra0 + 32) * 128 + ((ch ^ sa) * 16));
            short8 b0 = *(const short8*)((const char*)Bt + rb0 * 128        + ((ch ^ sb) * 16));
            short8 b1 = *(const short8*)((const char*)Bt + (rb0 + 32) * 128 + ((ch ^ sb) * 16));
            acc[0][0] = __builtin_amdgcn_mfma_f32_32x32x16_bf16(a0, b0, acc[0][0], 0, 0, 0);
            acc[0][1] = __builtin_amdgcn_mfma_f32_32x32x16_bf16(a0, b1, acc[0][1], 0, 0, 0);
            acc[1][0] = __builtin_amdgcn_mfma_f32_32x32x16_bf16(a1, b0, acc[1][0], 0, 0, 0);
            acc[1][1] = __builtin_amdgcn_mfma_f32_32x32x16_bf16(a1, b1, acc[1][1], 0, 0, 0);
        }
        __syncthreads();
    }

    const int j0 = code0 + wc * 64 + (lane & 31);
    const float c20 = c2[j0], c21 = c2[j0 + 32];
#pragma unroll
    for (int mi = 0; mi < 2; ++mi) {
#pragma unroll
        for (int reg = 0; reg < 16; ++reg) {
            const int rl = wr * 64 + mi * 32 + (reg & 3) + 8 * (reg >> 2) + 4 * kh;
            const float d0 = (4.0f + c20) - 2.0f * acc[mi][0][reg];
            const float d1 = (4.0f + c21) - 2.0f * acc[mi][1][reg];
            unsigned u0 = __float_as_uint(d0), u1 = __float_as_uint(d1);
            unsigned u = u0 < u1 ? u0 : u1;
#pragma unroll
            for (int m = 1; m <= 16; m <<= 1) {
                unsigned o = __shfl_xor(u, m, 64);
                if (o < u) u = o;
            }
            if ((lane & 31) == 0) atomicMin(&smin[rl], u);
        }
    }
    __syncthreads();
    if (tid < GBM) tmin[codetile * NROWS + row0 + tid] = smin[tid];
}

// ---------------- pass B: candidate tile selection (2E + tie margin) ------
__global__ __launch_bounds__(256) void k_select(
        const unsigned* __restrict__ tmin, const float* __restrict__ Z,
        int* __restrict__ cnt, int* __restrict__ list) {
    const int row = blockIdx.x * 256 + threadIdx.x;
    unsigned mn = 0xFFFFFFFFu;
    for (int t = 0; t < NTILE; ++t) {
        unsigned v = tmin[t * NROWS + row];
        if (v < mn) mn = v;
    }
    const float margin = 8.7e-5f * sqrtf(Z[row]) + 1.7e-4f;
    const float thr = __uint_as_float(mn) + margin;
    for (int t = 0; t < NTILE; ++t) {
        if (__uint_as_float(tmin[t * NROWS + row]) <= thr) {
            int p = atomicAdd(&cnt[t], 1);
            list[t * NROWS + p] = row;
        }
    }
}

// ---------------- pass C: exact 6-split MFMA rescore on gathered rows -----
// Per (tile, row-chunk of 128): 128x128xK=3072 GEMM, product blocks in the
// round-5 order [hi*MID, mid*HI, mid*MID, hi*LO, lo*HI, hi*HI] -> per-pair
// acc bitwise-identical to the round-5 kernel that passed absmax 0.
// Rows gathered via per-lane global addresses (global_load_lds src is
// per-lane). Padded slots duplicate rows[0]: exact d, atomicMin-harmless.
__global__ __launch_bounds__(256) void k_rescore_mfma(
        const unsigned short* __restrict__ Xe, const unsigned short* __restrict__ We,
        const float* __restrict__ Z, const float* __restrict__ c2,
        const int* __restrict__ cnt, const int* __restrict__ list,
        unsigned long long* __restrict__ keys) {
    __shared__ __align__(16) unsigned short At[GBM * GBK];
    __shared__ __align__(16) unsigned short Bt[GBN * GBK];
    __shared__ int rl_s[GBM];
    __shared__ float Zs[GBM];

    const int tile = blockIdx.x;
    const int n = cnt[tile];
    if (n == 0) return;
    const int* rows = list + tile * NROWS;
    const int tid = threadIdx.x;
    const int lane = tid & 63, wid = tid >> 6;
    const int wr = wid >> 1, wc = wid & 1;
    const int code0 = tile * 128;

    const int ra0 = wr * 64 + (lane & 31);
    const int rb0 = wc * 64 + (lane & 31);
    const int kh  = lane >> 5;
    const int sa  = ra0 & 7, sb = rb0 & 7;
    const int j0 = code0 + wc * 64 + (lane & 31);
    const float c20 = c2[j0], c21 = c2[j0 + 32];

    for (int chk = (int)blockIdx.y; chk * GBM < n; chk += 8) {
        __syncthreads();   // previous iteration fully done before rl_s/LDS reuse
        if (tid < GBM) {
            int ri = chk * GBM + tid;
            int r = rows[ri < n ? ri : 0];
            rl_s[tid] = r;
            Zs[tid] = Z[r];
        }
        __syncthreads();

        size_t aoff[4], boff[4];
#pragma unroll
        for (int i = 0; i < 4; ++i) {
            int chunk = i * 256 + tid;
            int row   = chunk >> 3;
            int kcs   = (chunk & 7) ^ (row & 7);
            aoff[i] = (size_t)rl_s[row] * K3 + kcs * 8;
            boff[i] = (size_t)(code0 + row) * K3 + kcs * 8;
        }

        f32x16 acc[2][2];
#pragma unroll
        for (int i = 0; i < 2; ++i)
#pragma unroll
            for (int j = 0; j < 2; ++j)
#pragma unroll
                for (int r = 0; r < 16; ++r) acc[i][j][r] = 0.0f;

#pragma unroll
        for (int bt = 0; bt < 6; ++bt) {
            // product-block lookup (compile-time: bt loop fully unrolled)
            const int ao = (bt == 1 || bt == 2) ? EDIM : (bt == 4 ? 2 * EDIM : 0);
            const int bo = (bt == 0 || bt == 2) ? EDIM : (bt == 3 ? 2 * EDIM : 0);
            for (int kc = 0; kc < 8; ++kc) {
                const int ko = ao + kc * GBK;
                const int kob = bo + kc * GBK;
#pragma unroll
                for (int i = 0; i < 4; ++i) {
                    gld16(Xe + aoff[i] + ko,  (char*)At + i * 4096 + wid * 1024);
                    gld16(We + boff[i] + kob, (char*)Bt + i * 4096 + wid * 1024);
                }
                __syncthreads();
#pragma unroll
                for (int ks = 0; ks < 4; ++ks) {
                    const int ch = ks * 2 + kh;
                    short8 a0 = *(const short8*)((const char*)At + ra0 * 128        + ((ch ^ sa) * 16));
                    short8 a1 = *(const short8*)((const char*)At + (ra0 + 32) * 128 + ((ch ^ sa) * 16));
                    short8 b0 = *(const short8*)((const char*)Bt + rb0 * 128        + ((ch ^ sb) * 16));
                    short8 b1 = *(const short8*)((const char*)Bt + (rb0 + 32) * 128 + ((ch ^ sb) * 16));
                    acc[0][0] = __builtin_amdgcn_mfma_f32_32x32x16_bf16(a0, b0, acc[0][0], 0, 0, 0);
                    acc[0][1] = __builtin_amdgcn_mfma_f32_32x32x16_bf16(a0, b1, acc[0][1], 0, 0, 0);
                    acc[1][0] = __builtin_amdgcn_mfma_f32_32x32x16_bf16(a1, b0, acc[1][0], 0, 0, 0);
                    acc[1][1] = __builtin_amdgcn_mfma_f32_32x32x16_bf16(a1, b1, acc[1][1], 0, 0, 0);
                }
                __syncthreads();
            }
        }

        // epilogue: exact d = (Z + c2) - 2*m, packed-key argmin
#pragma unroll
        for (int mi = 0; mi < 2; ++mi) {
#pragma unroll
            for (int reg = 0; reg < 16; ++reg) {
                const int rl = wr * 64 + mi * 32 + (reg & 3) + 8 * (reg >> 2) + 4 * kh;
                const float Zr = Zs[rl];
                const float d0 = (Zr + c20) - 2.0f * acc[mi][0][reg];
                const float d1 = (Zr + c21) - 2.0f * acc[mi][1][reg];
                unsigned long long k0 = (((unsigned long long)__float_as_uint(d0)) << 13) | (unsigned)j0;
                unsigned long long k1 = (((unsigned long long)__float_as_uint(d1)) << 13) | (unsigned)(j0 + 32);
                unsigned long long k = k0 < k1 ? k0 : k1;
#pragma unroll
                for (int m = 1; m <= 16; m <<= 1) {
                    unsigned long long o = __shfl_xor(k, m, 64);
                    if (o < k) k = o;
                }
                if ((lane & 31) == 0) atomicMin(&keys[rl_s[rl]], k);
            }
        }
    }
}

// ---------------- gather / loss partials / finalize ----------------
__global__ __launch_bounds__(256) void k_gather(
        const float* __restrict__ x, const float* __restrict__ W,
        const unsigned long long* __restrict__ keys,
        float* __restrict__ out, double* __restrict__ part) {
    const int tid = threadIdx.x;
    const int row = blockIdx.x * 8 + (tid >> 5);
    const int c = tid & 31;
    const int idx = (int)(keys[row] & 0x1FFFull);

    const float* wrow = W + (size_t)idx * EDIM;
    const float* xrow = x + (size_t)row * EDIM;
    float* orow = out + (size_t)row * EDIM;

    double lsum = 0.0;
#pragma unroll
    for (int v = 0; v < 4; ++v) {
        const int d = c * 4 + v * 128;
        float4 xv = *(const float4*)(xrow + d);
        float4 wv = *(const float4*)(wrow + d);
        float t0 = wv.x - xv.x, t1 = wv.y - xv.y, t2 = wv.z - xv.z, t3 = wv.w - xv.w;
        float4 ov = { xv.x + t0, xv.y + t1, xv.z + t2, xv.w + t3 };
        *(float4*)(orow + d) = ov;
        lsum += (double)t0 * t0 + (double)t1 * t1 + (double)t2 * t2 + (double)t3 * t3;
    }
    if (c == 0) out[XQSZ + 1 + row] = (float)idx;

#pragma unroll
    for (int off = 32; off > 0; off >>= 1) lsum += __shfl_down(lsum, off, 64);
    __shared__ double pb[4];
    if ((tid & 63) == 0) pb[tid >> 6] = lsum;
    __syncthreads();
    if (tid == 0) part[blockIdx.x] = pb[0] + pb[1] + pb[2] + pb[3];
}

__global__ __launch_bounds__(256) void k_finalize(float* __restrict__ out,
        const double* __restrict__ part) {
    const int tid = threadIdx.x;
    double s = 0.0;
    for (int i = tid; i < 2048; i += 256) s += part[i];
#pragma unroll
    for (int off = 32; off > 0; off >>= 1) s += __shfl_down(s, off, 64);
    __shared__ double pb[4];
    if ((tid & 63) == 0) pb[tid >> 6] = s;
    __syncthreads();
    if (tid == 0) out[XQSZ] = (float)(0.25 * (pb[0] + pb[1] + pb[2] + pb[3]) / (double)XQSZ);
}

extern "C" void kernel_launch(void* const* d_in, const int* in_sizes, int n_in,
                              void* d_out, int out_size, void* d_ws, size_t ws_size,
                              hipStream_t stream) {
    const float* x = (const float*)d_in[0];
    const float* W = (const float*)d_in[3];
    float* out = (float*)d_out;
    char* ws = (char*)d_ws;

    double* part = (double*)(ws + OFF_PART);
    float* Z    = (float*)(ws + OFF_Z);
    float* c2   = (float*)(ws + OFF_C2);
    unsigned long long* keys = (unsigned long long*)(ws + OFF_KEYS);
    unsigned* tmin = (unsigned*)(ws + OFF_TMIN);
    int* cnt  = (int*)(ws + OFF_CNT);
    int* list = (int*)(ws + OFF_LIST);
    unsigned short* Xe = (unsigned short*)(ws + OFF_XE);
    unsigned short* We = (unsigned short*)(ws + OFF_WE);

    hipMemsetAsync(keys, 0xFF, NROWS * sizeof(unsigned long long), stream);
    hipMemsetAsync(cnt, 0, NTILE * sizeof(int), stream);
    k_rownorm<<<NROWS / 256, 256, 0, stream>>>(x, Z, NROWS);
    k_rownorm<<<NE / 256, 256, 0, stream>>>(W, c2, NE);
    k_split3<<<(NROWS * 128) / 256, 256, 0, stream>>>(x, Xe, NROWS);
    k_split3<<<(NE * 128) / 256, 256, 0, stream>>>(W, We, NE);
    k_argmin_hi<<<(NROWS / GBM) * (NE / GBN), 256, 0, stream>>>(Xe, We, c2, tmin);
    k_select<<<NROWS / 256, 256, 0, stream>>>(tmin, Z, cnt, list);
    k_rescore_mfma<<<dim3(NTILE, 8), 256, 0, stream>>>(Xe, We, Z, c2, cnt, list, keys);
    k_gather<<<NROWS / 8, 256, 0, stream>>>(x, W, keys, out, part);
    k_finalize<<<1, 256, 0, stream>>>(out, part);
}

// Round 9
// 583.076 us; speedup vs baseline: 2.6535x; 1.1656x over previous
//
#include <hip/hip_runtime.h>
#include <cstdint>
#include <cstddef>

#define EDIM  512
#define NROWS 16384
#define NE    8192
#define XQSZ  (NROWS * EDIM)   // 8388608
#define NTILE 64               // 8192 codes / 128 per tile
#define K3    1536             // 3-block split: [hi, mid, lo]

// workspace byte offsets
#define OFF_PART  0                          // 2048 doubles
#define OFF_Z     16384
#define OFF_C2    81920
#define OFF_KEYS  114688
#define OFF_TMIN  245760                     // NROWS*NTILE*4 = 4 MB
#define OFF_CNT   4440064
#define OFF_LIST  4441088                    // NROWS*NTILE*4 = 4 MB
#define OFF_XE    8635392                    // NROWS*K3*2 = 48 MB
#define OFF_WE    58967040                   // NE*K3*2 = 24 MB (end ~84 MB)

typedef __attribute__((ext_vector_type(8)))  short          short8;
typedef __attribute__((ext_vector_type(16))) float          f32x16;
typedef __attribute__((ext_vector_type(4)))  unsigned short u16x4;

// ---------------- rownorm (numpy pairwise order) ----------------
__global__ void k_rownorm(const float* __restrict__ in, float* __restrict__ out, int nrows) {
#pragma clang fp contract(off)
    int row = blockIdx.x * blockDim.x + threadIdx.x;
    if (row >= nrows) return;
    const float* p = in + (size_t)row * EDIM;
    float S[4];
#pragma unroll
    for (int b = 0; b < 4; ++b) {
        const float* q = p + b * 128;
        float r[8];
#pragma unroll
        for (int j = 0; j < 8; ++j) { float v = q[j]; r[j] = v * v; }
        for (int i = 8; i < 128; i += 8) {
#pragma unroll
            for (int j = 0; j < 8; ++j) { float v = q[i + j]; r[j] = r[j] + v * v; }
        }
        S[b] = ((r[0] + r[1]) + (r[2] + r[3])) + ((r[4] + r[5]) + (r[6] + r[7]));
    }
    out[row] = (S[0] + S[1]) + (S[2] + S[3]);
}

// ---------------- bf16 3-way split [hi, mid, lo], exact ----------------
__device__ __forceinline__ unsigned short f2bf(float f) {
    unsigned u = __float_as_uint(f);
    return (unsigned short)((u + 0x7FFFu + ((u >> 16) & 1u)) >> 16);
}
__device__ __forceinline__ float bf2f(unsigned short h) {
    return __uint_as_float(((unsigned)h) << 16);
}

__global__ __launch_bounds__(256) void k_split3(const float* __restrict__ in,
        unsigned short* __restrict__ outp, int nrows) {
    int e = blockIdx.x * 256 + threadIdx.x;
    int row = e >> 7;               // 128 float4-groups per row
    int d0  = (e & 127) << 2;
    if (row >= nrows) return;
    float4 v = *(const float4*)(in + (size_t)row * EDIM + d0);
    float vv[4] = {v.x, v.y, v.z, v.w};
    u16x4 H, M, L;
#pragma unroll
    for (int i = 0; i < 4; ++i) {
        float f = vv[i];
        unsigned short h = f2bf(f);
        float r1 = f - bf2f(h);          // exact
        unsigned short m = f2bf(r1);
        float r2 = r1 - bf2f(m);         // exact
        L[i] = f2bf(r2); H[i] = h; M[i] = m;
    }
    unsigned short* o = outp + (size_t)row * K3 + d0;
    *(u16x4*)(o) = H; *(u16x4*)(o + EDIM) = M; *(u16x4*)(o + 2 * EDIM) = L;
}

// ---------------- shared MFMA helpers ----------------
__device__ __forceinline__ void gld16(const void* g, void* l) {
    __builtin_amdgcn_global_load_lds((const __attribute__((address_space(1))) void*)g,
                                     (__attribute__((address_space(3))) void*)l, 16, 0, 0);
}

#define GBM 128
#define GBN 128
#define GBK 64

// ---------------- pass A: hi-GEMM (block 0 of Xe/We), per-(row,tile) min ----
__global__ __launch_bounds__(256) void k_argmin_hi(
        const unsigned short* __restrict__ Xe, const unsigned short* __restrict__ We,
        const float* __restrict__ c2, unsigned* __restrict__ tmin) {
    __shared__ __align__(16) unsigned short At[GBM * GBK];
    __shared__ __align__(16) unsigned short Bt[GBN * GBK];
    __shared__ unsigned smin[GBM];

    const int tid = threadIdx.x;
    const int lane = tid & 63, wid = tid >> 6;
    const int wr = wid >> 1, wc = wid & 1;

    const int bid = blockIdx.x;
    const int swz = (bid & 7) * 1024 + (bid >> 3);   // 8192 % 8 == 0, bijective
    const int rowtile = swz & 127, codetile = swz >> 7;
    const int row0 = rowtile * GBM, code0 = codetile * GBN;

    if (tid < GBM) smin[tid] = 0xFFFFFFFFu;

    f32x16 acc[2][2];
#pragma unroll
    for (int i = 0; i < 2; ++i)
#pragma unroll
        for (int j = 0; j < 2; ++j)
#pragma unroll
            for (int r = 0; r < 16; ++r) acc[i][j][r] = 0.0f;

    size_t ga[4], gb[4];
#pragma unroll
    for (int i = 0; i < 4; ++i) {
        int chunk = i * 256 + tid;
        int row   = chunk >> 3;
        int kcs   = (chunk & 7) ^ (row & 7);
        ga[i] = (size_t)(row0 + row) * K3 + kcs * 8;
        gb[i] = (size_t)(code0 + row) * K3 + kcs * 8;
    }

    const int ra0 = wr * 64 + (lane & 31);
    const int rb0 = wc * 64 + (lane & 31);
    const int kh  = lane >> 5;
    const int sa  = ra0 & 7, sb = rb0 & 7;

    for (int kt = 0; kt < EDIM / GBK; ++kt) {
        const size_t ko = (size_t)kt * GBK;
#pragma unroll
        for (int i = 0; i < 4; ++i) {
            gld16(Xe + ga[i] + ko, (char*)At + i * 4096 + wid * 1024);
            gld16(We + gb[i] + ko, (char*)Bt + i * 4096 + wid * 1024);
        }
        __syncthreads();
#pragma unroll
        for (int ks = 0; ks < 4; ++ks) {
            const int ch = ks * 2 + kh;
            short8 a0 = *(const short8*)((const char*)At + ra0 * 128        + ((ch ^ sa) * 16));
            short8 a1 = *(const short8*)((const char*)At + (ra0 + 32) * 128 + ((ch ^ sa) * 16));
            short8 b0 = *(const short8*)((const char*)Bt + rb0 * 128        + ((ch ^ sb) * 16));
            short8 b1 = *(const short8*)((const char*)Bt + (rb0 + 32) * 128 + ((ch ^ sb) * 16));
            acc[0][0] = __builtin_amdgcn_mfma_f32_32x32x16_bf16(a0, b0, acc[0][0], 0, 0, 0);
            acc[0][1] = __builtin_amdgcn_mfma_f32_32x32x16_bf16(a0, b1, acc[0][1], 0, 0, 0);
            acc[1][0] = __builtin_amdgcn_mfma_f32_32x32x16_bf16(a1, b0, acc[1][0], 0, 0, 0);
            acc[1][1] = __builtin_amdgcn_mfma_f32_32x32x16_bf16(a1, b1, acc[1][1], 0, 0, 0);
        }
        __syncthreads();
    }

    const int j0 = code0 + wc * 64 + (lane & 31);
    const float c20 = c2[j0], c21 = c2[j0 + 32];
#pragma unroll
    for (int mi = 0; mi < 2; ++mi) {
#pragma unroll
        for (int reg = 0; reg < 16; ++reg) {
            const int rl = wr * 64 + mi * 32 + (reg & 3) + 8 * (reg >> 2) + 4 * kh;
            const float d0 = (4.0f + c20) - 2.0f * acc[mi][0][reg];
            const float d1 = (4.0f + c21) - 2.0f * acc[mi][1][reg];
            unsigned u0 = __float_as_uint(d0), u1 = __float_as_uint(d1);
            unsigned u = u0 < u1 ? u0 : u1;
#pragma unroll
            for (int m = 1; m <= 16; m <<= 1) {
                unsigned o = __shfl_xor(u, m, 64);
                if (o < u) u = o;
            }
            if ((lane & 31) == 0) atomicMin(&smin[rl], u);
        }
    }
    __syncthreads();
    if (tid < GBM) tmin[codetile * NROWS + row0 + tid] = smin[tid];
}

// ---------------- pass B: candidate tile selection ----------------
// Rigorous margin: |d - d~| <= 2 * 2^-8 * 2 * ||x|| * ||w||max
//   = 2^-7 * sqrt(Z) * 2.766e-3 * 2 = 4.32e-5 * sqrt(Z)   (2E, tight)
// + f32 tie/rounding window 1.7e-4. Empirically validated in round 6.
__global__ __launch_bounds__(256) void k_select(
        const unsigned* __restrict__ tmin, const float* __restrict__ Z,
        int* __restrict__ cnt, int* __restrict__ list) {
    const int row = blockIdx.x * 256 + threadIdx.x;
    unsigned mn = 0xFFFFFFFFu;
    for (int t = 0; t < NTILE; ++t) {
        unsigned v = tmin[t * NROWS + row];
        if (v < mn) mn = v;
    }
    const float margin = 4.35e-5f * sqrtf(Z[row]) + 1.7e-4f;
    const float thr = __uint_as_float(mn) + margin;
    for (int t = 0; t < NTILE; ++t) {
        if (__uint_as_float(tmin[t * NROWS + row]) <= thr) {
            int p = atomicAdd(&cnt[t], 1);
            list[t * NROWS + p] = row;
        }
    }
}

// ---------------- pass C: exact 6-split MFMA rescore on gathered rows -----
// Per (tile, row-chunk of 128): 128x128xK=3072 GEMM, product blocks in the
// round-5 order [hi*MID, mid*HI, mid*MID, hi*LO, lo*HI, hi*HI] -> per-pair
// acc bitwise-identical to the round-5 kernel that passed absmax 0.
// grid (NTILE, 16): 1024 blocks -> ~4 blocks/CU (33 KB LDS), latency hidden
// by cross-block overlap; same-tile chunks land on one XCD (ids = x + 64y,
// same x => same id mod 8) so the shared We tile stays L2-resident.
__global__ __launch_bounds__(256) void k_rescore_mfma(
        const unsigned short* __restrict__ Xe, const unsigned short* __restrict__ We,
        const float* __restrict__ Z, const float* __restrict__ c2,
        const int* __restrict__ cnt, const int* __restrict__ list,
        unsigned long long* __restrict__ keys) {
    __shared__ __align__(16) unsigned short At[GBM * GBK];
    __shared__ __align__(16) unsigned short Bt[GBN * GBK];
    __shared__ int rl_s[GBM];
    __shared__ float Zs[GBM];

    const int tile = blockIdx.x;
    const int n = cnt[tile];
    if (n == 0) return;
    const int* rows = list + tile * NROWS;
    const int tid = threadIdx.x;
    const int lane = tid & 63, wid = tid >> 6;
    const int wr = wid >> 1, wc = wid & 1;
    const int code0 = tile * 128;

    const int ra0 = wr * 64 + (lane & 31);
    const int rb0 = wc * 64 + (lane & 31);
    const int kh  = lane >> 5;
    const int sa  = ra0 & 7, sb = rb0 & 7;
    const int j0 = code0 + wc * 64 + (lane & 31);
    const float c20 = c2[j0], c21 = c2[j0 + 32];

    for (int chk = (int)blockIdx.y; chk * GBM < n; chk += 16) {
        __syncthreads();   // previous iteration fully done before rl_s/LDS reuse
        if (tid < GBM) {
            int ri = chk * GBM + tid;
            int r = rows[ri < n ? ri : 0];
            rl_s[tid] = r;
            Zs[tid] = Z[r];
        }
        __syncthreads();

        size_t aoff[4], boff[4];
#pragma unroll
        for (int i = 0; i < 4; ++i) {
            int chunk = i * 256 + tid;
            int row   = chunk >> 3;
            int kcs   = (chunk & 7) ^ (row & 7);
            aoff[i] = (size_t)rl_s[row] * K3 + kcs * 8;
            boff[i] = (size_t)(code0 + row) * K3 + kcs * 8;
        }

        f32x16 acc[2][2];
#pragma unroll
        for (int i = 0; i < 2; ++i)
#pragma unroll
            for (int j = 0; j < 2; ++j)
#pragma unroll
                for (int r = 0; r < 16; ++r) acc[i][j][r] = 0.0f;

#pragma unroll
        for (int bt = 0; bt < 6; ++bt) {
            const int ao = (bt == 1 || bt == 2) ? EDIM : (bt == 4 ? 2 * EDIM : 0);
            const int bo = (bt == 0 || bt == 2) ? EDIM : (bt == 3 ? 2 * EDIM : 0);
            for (int kc = 0; kc < 8; ++kc) {
                const int ko = ao + kc * GBK;
                const int kob = bo + kc * GBK;
#pragma unroll
                for (int i = 0; i < 4; ++i) {
                    gld16(Xe + aoff[i] + ko,  (char*)At + i * 4096 + wid * 1024);
                    gld16(We + boff[i] + kob, (char*)Bt + i * 4096 + wid * 1024);
                }
                __syncthreads();
#pragma unroll
                for (int ks = 0; ks < 4; ++ks) {
                    const int ch = ks * 2 + kh;
                    short8 a0 = *(const short8*)((const char*)At + ra0 * 128        + ((ch ^ sa) * 16));
                    short8 a1 = *(const short8*)((const char*)At + (ra0 + 32) * 128 + ((ch ^ sa) * 16));
                    short8 b0 = *(const short8*)((const char*)Bt + rb0 * 128        + ((ch ^ sb) * 16));
                    short8 b1 = *(const short8*)((const char*)Bt + (rb0 + 32) * 128 + ((ch ^ sb) * 16));
                    acc[0][0] = __builtin_amdgcn_mfma_f32_32x32x16_bf16(a0, b0, acc[0][0], 0, 0, 0);
                    acc[0][1] = __builtin_amdgcn_mfma_f32_32x32x16_bf16(a0, b1, acc[0][1], 0, 0, 0);
                    acc[1][0] = __builtin_amdgcn_mfma_f32_32x32x16_bf16(a1, b0, acc[1][0], 0, 0, 0);
                    acc[1][1] = __builtin_amdgcn_mfma_f32_32x32x16_bf16(a1, b1, acc[1][1], 0, 0, 0);
                }
                __syncthreads();
            }
        }

        // epilogue: exact d = (Z + c2) - 2*m, packed-key argmin
#pragma unroll
        for (int mi = 0; mi < 2; ++mi) {
#pragma unroll
            for (int reg = 0; reg < 16; ++reg) {
                const int rl = wr * 64 + mi * 32 + (reg & 3) + 8 * (reg >> 2) + 4 * kh;
                const float Zr = Zs[rl];
                const float d0 = (Zr + c20) - 2.0f * acc[mi][0][reg];
                const float d1 = (Zr + c21) - 2.0f * acc[mi][1][reg];
                unsigned long long k0 = (((unsigned long long)__float_as_uint(d0)) << 13) | (unsigned)j0;
                unsigned long long k1 = (((unsigned long long)__float_as_uint(d1)) << 13) | (unsigned)(j0 + 32);
                unsigned long long k = k0 < k1 ? k0 : k1;
#pragma unroll
                for (int m = 1; m <= 16; m <<= 1) {
                    unsigned long long o = __shfl_xor(k, m, 64);
                    if (o < k) k = o;
                }
                if ((lane & 31) == 0) atomicMin(&keys[rl_s[rl]], k);
            }
        }
    }
}

// ---------------- gather / loss partials / finalize ----------------
__global__ __launch_bounds__(256) void k_gather(
        const float* __restrict__ x, const float* __restrict__ W,
        const unsigned long long* __restrict__ keys,
        float* __restrict__ out, double* __restrict__ part) {
    const int tid = threadIdx.x;
    const int row = blockIdx.x * 8 + (tid >> 5);
    const int c = tid & 31;
    const int idx = (int)(keys[row] & 0x1FFFull);

    const float* wrow = W + (size_t)idx * EDIM;
    const float* xrow = x + (size_t)row * EDIM;
    float* orow = out + (size_t)row * EDIM;

    double lsum = 0.0;
#pragma unroll
    for (int v = 0; v < 4; ++v) {
        const int d = c * 4 + v * 128;
        float4 xv = *(const float4*)(xrow + d);
        float4 wv = *(const float4*)(wrow + d);
        float t0 = wv.x - xv.x, t1 = wv.y - xv.y, t2 = wv.z - xv.z, t3 = wv.w - xv.w;
        float4 ov = { xv.x + t0, xv.y + t1, xv.z + t2, xv.w + t3 };
        *(float4*)(orow + d) = ov;
        lsum += (double)t0 * t0 + (double)t1 * t1 + (double)t2 * t2 + (double)t3 * t3;
    }
    if (c == 0) out[XQSZ + 1 + row] = (float)idx;

#pragma unroll
    for (int off = 32; off > 0; off >>= 1) lsum += __shfl_down(lsum, off, 64);
    __shared__ double pb[4];
    if ((tid & 63) == 0) pb[tid >> 6] = lsum;
    __syncthreads();
    if (tid == 0) part[blockIdx.x] = pb[0] + pb[1] + pb[2] + pb[3];
}

__global__ __launch_bounds__(256) void k_finalize(float* __restrict__ out,
        const double* __restrict__ part) {
    const int tid = threadIdx.x;
    double s = 0.0;
    for (int i = tid; i < 2048; i += 256) s += part[i];
#pragma unroll
    for (int off = 32; off > 0; off >>= 1) s += __shfl_down(s, off, 64);
    __shared__ double pb[4];
    if ((tid & 63) == 0) pb[tid >> 6] = s;
    __syncthreads();
    if (tid == 0) out[XQSZ] = (float)(0.25 * (pb[0] + pb[1] + pb[2] + pb[3]) / (double)XQSZ);
}

extern "C" void kernel_launch(void* const* d_in, const int* in_sizes, int n_in,
                              void* d_out, int out_size, void* d_ws, size_t ws_size,
                              hipStream_t stream) {
    const float* x = (const float*)d_in[0];
    const float* W = (const float*)d_in[3];
    float* out = (float*)d_out;
    char* ws = (char*)d_ws;

    double* part = (double*)(ws + OFF_PART);
    float* Z    = (float*)(ws + OFF_Z);
    float* c2   = (float*)(ws + OFF_C2);
    unsigned long long* keys = (unsigned long long*)(ws + OFF_KEYS);
    unsigned* tmin = (unsigned*)(ws + OFF_TMIN);
    int* cnt  = (int*)(ws + OFF_CNT);
    int* list = (int*)(ws + OFF_LIST);
    unsigned short* Xe = (unsigned short*)(ws + OFF_XE);
    unsigned short* We = (unsigned short*)(ws + OFF_WE);

    hipMemsetAsync(keys, 0xFF, NROWS * sizeof(unsigned long long), stream);
    hipMemsetAsync(cnt, 0, NTILE * sizeof(int), stream);
    k_rownorm<<<NROWS / 256, 256, 0, stream>>>(x, Z, NROWS);
    k_rownorm<<<NE / 256, 256, 0, stream>>>(W, c2, NE);
    k_split3<<<(NROWS * 128) / 256, 256, 0, stream>>>(x, Xe, NROWS);
    k_split3<<<(NE * 128) / 256, 256, 0, stream>>>(W, We, NE);
    k_argmin_hi<<<(NROWS / GBM) * (NE / GBN), 256, 0, stream>>>(Xe, We, c2, tmin);
    k_select<<<NROWS / 256, 256, 0, stream>>>(tmin, Z, cnt, list);
    k_rescore_mfma<<<dim3(NTILE, 16), 256, 0, stream>>>(Xe, We, Z, c2, cnt, list, keys);
    k_gather<<<NROWS / 8, 256, 0, stream>>>(x, W, keys, out, part);
    k_finalize<<<1, 256, 0, stream>>>(out, part);
}

// Round 10
// 535.558 us; speedup vs baseline: 2.8889x; 1.0887x over previous
//
#include <hip/hip_runtime.h>
#include <cstdint>
#include <cstddef>

#define EDIM  512
#define NROWS 16384
#define NE    8192
#define XQSZ  (NROWS * EDIM)   // 8388608
#define NTILE 64               // 8192 codes / 128 per tile
#define K3    1536             // 3-block split: [hi, mid, lo]

// workspace byte offsets
#define OFF_PART  0                          // 2048 doubles
#define OFF_Z     16384
#define OFF_C2    81920
#define OFF_KEYS  114688
#define OFF_TMIN  245760                     // NROWS*NTILE*4 = 4 MB
#define OFF_CNT   4440064
#define OFF_LIST  4441088                    // NROWS*NTILE*4 = 4 MB
#define OFF_XE    8635392                    // NROWS*K3*2 = 48 MB
#define OFF_WE    58967040                   // NE*K3*2 = 24 MB (end ~84 MB)

typedef __attribute__((ext_vector_type(8)))  short          short8;
typedef __attribute__((ext_vector_type(16))) float          f32x16;
typedef __attribute__((ext_vector_type(4)))  unsigned short u16x4;

// ---------------- rownorm (numpy pairwise order) ----------------
__global__ void k_rownorm(const float* __restrict__ in, float* __restrict__ out, int nrows) {
#pragma clang fp contract(off)
    int row = blockIdx.x * blockDim.x + threadIdx.x;
    if (row >= nrows) return;
    const float* p = in + (size_t)row * EDIM;
    float S[4];
#pragma unroll
    for (int b = 0; b < 4; ++b) {
        const float* q = p + b * 128;
        float r[8];
#pragma unroll
        for (int j = 0; j < 8; ++j) { float v = q[j]; r[j] = v * v; }
        for (int i = 8; i < 128; i += 8) {
#pragma unroll
            for (int j = 0; j < 8; ++j) { float v = q[i + j]; r[j] = r[j] + v * v; }
        }
        S[b] = ((r[0] + r[1]) + (r[2] + r[3])) + ((r[4] + r[5]) + (r[6] + r[7]));
    }
    out[row] = (S[0] + S[1]) + (S[2] + S[3]);
}

// ---------------- bf16 3-way split [hi, mid, lo], exact ----------------
__device__ __forceinline__ unsigned short f2bf(float f) {
    unsigned u = __float_as_uint(f);
    return (unsigned short)((u + 0x7FFFu + ((u >> 16) & 1u)) >> 16);
}
__device__ __forceinline__ float bf2f(unsigned short h) {
    return __uint_as_float(((unsigned)h) << 16);
}

__global__ __launch_bounds__(256) void k_split3(const float* __restrict__ in,
        unsigned short* __restrict__ outp, int nrows) {
    int e = blockIdx.x * 256 + threadIdx.x;
    int row = e >> 7;               // 128 float4-groups per row
    int d0  = (e & 127) << 2;
    if (row >= nrows) return;
    float4 v = *(const float4*)(in + (size_t)row * EDIM + d0);
    float vv[4] = {v.x, v.y, v.z, v.w};
    u16x4 H, M, L;
#pragma unroll
    for (int i = 0; i < 4; ++i) {
        float f = vv[i];
        unsigned short h = f2bf(f);
        float r1 = f - bf2f(h);          // exact
        unsigned short m = f2bf(r1);
        float r2 = r1 - bf2f(m);         // exact
        L[i] = f2bf(r2); H[i] = h; M[i] = m;
    }
    unsigned short* o = outp + (size_t)row * K3 + d0;
    *(u16x4*)(o) = H; *(u16x4*)(o + EDIM) = M; *(u16x4*)(o + 2 * EDIM) = L;
}

// ---------------- shared MFMA helpers ----------------
__device__ __forceinline__ void gld16(const void* g, void* l) {
    __builtin_amdgcn_global_load_lds((const __attribute__((address_space(1))) void*)g,
                                     (__attribute__((address_space(3))) void*)l, 16, 0, 0);
}

#define GBM 128
#define GBN 128
#define GBK 64

// ---------------- pass A: hi-GEMM, SWAPPED orientation ----------------
// acc[mi][nj] = mfma(code_frag_mi, x_frag_nj): C rows = codes, cols = xrows.
// Per lane: 32 codes for a fixed xrow -> per-lane fminf chain, no shuffles.
__global__ __launch_bounds__(256) void k_argmin_hi(
        const unsigned short* __restrict__ Xe, const unsigned short* __restrict__ We,
        const float* __restrict__ c2, unsigned* __restrict__ tmin) {
    __shared__ __align__(16) unsigned short At[GBM * GBK];   // x rows
    __shared__ __align__(16) unsigned short Bt[GBN * GBK];   // code rows
    __shared__ unsigned smin[GBM];
    __shared__ float cs[GBN];                                // 4 + c2

    const int tid = threadIdx.x;
    const int lane = tid & 63, wid = tid >> 6;
    const int wr = wid >> 1, wc = wid & 1;

    const int bid = blockIdx.x;
    const int swz = (bid & 7) * 1024 + (bid >> 3);   // 8192 % 8 == 0, bijective
    const int rowtile = swz & 127, codetile = swz >> 7;
    const int row0 = rowtile * GBM, code0 = codetile * GBN;

    if (tid < GBM) smin[tid] = 0xFFFFFFFFu;
    if (tid < GBN) cs[tid] = 4.0f + c2[code0 + tid];

    f32x16 acc[2][2];
#pragma unroll
    for (int i = 0; i < 2; ++i)
#pragma unroll
        for (int j = 0; j < 2; ++j)
#pragma unroll
            for (int r = 0; r < 16; ++r) acc[i][j][r] = 0.0f;

    size_t ga[4], gb[4];
#pragma unroll
    for (int i = 0; i < 4; ++i) {
        int chunk = i * 256 + tid;
        int row   = chunk >> 3;
        int kcs   = (chunk & 7) ^ (row & 7);
        ga[i] = (size_t)(row0 + row) * K3 + kcs * 8;
        gb[i] = (size_t)(code0 + row) * K3 + kcs * 8;
    }

    const int cb0 = wr * 64 + (lane & 31);   // code-side (M) row in Bt
    const int xa0 = wc * 64 + (lane & 31);   // x-side (N) row in At
    const int kh  = lane >> 5;
    const int sb  = cb0 & 7, sa = xa0 & 7;

    for (int kt = 0; kt < EDIM / GBK; ++kt) {
        const size_t ko = (size_t)kt * GBK;
#pragma unroll
        for (int i = 0; i < 4; ++i) {
            gld16(Xe + ga[i] + ko, (char*)At + i * 4096 + wid * 1024);
            gld16(We + gb[i] + ko, (char*)Bt + i * 4096 + wid * 1024);
        }
        __syncthreads();
#pragma unroll
        for (int ks = 0; ks < 4; ++ks) {
            const int ch = ks * 2 + kh;
            short8 c0 = *(const short8*)((const char*)Bt + cb0 * 128        + ((ch ^ sb) * 16));
            short8 c1 = *(const short8*)((const char*)Bt + (cb0 + 32) * 128 + ((ch ^ sb) * 16));
            short8 x0 = *(const short8*)((const char*)At + xa0 * 128        + ((ch ^ sa) * 16));
            short8 x1 = *(const short8*)((const char*)At + (xa0 + 32) * 128 + ((ch ^ sa) * 16));
            acc[0][0] = __builtin_amdgcn_mfma_f32_32x32x16_bf16(c0, x0, acc[0][0], 0, 0, 0);
            acc[0][1] = __builtin_amdgcn_mfma_f32_32x32x16_bf16(c0, x1, acc[0][1], 0, 0, 0);
            acc[1][0] = __builtin_amdgcn_mfma_f32_32x32x16_bf16(c1, x0, acc[1][0], 0, 0, 0);
            acc[1][1] = __builtin_amdgcn_mfma_f32_32x32x16_bf16(c1, x1, acc[1][1], 0, 0, 0);
        }
        __syncthreads();
    }

    // epilogue: d~ = (4 + c2[code]) - 2*acc; per-lane min over 32 codes
    const int kh4 = kh * 4;
#pragma unroll
    for (int nj = 0; nj < 2; ++nj) {
        float dmin = 3.4e38f;
#pragma unroll
        for (int mi = 0; mi < 2; ++mi) {
#pragma unroll
            for (int q = 0; q < 4; ++q) {
                const float4 cq = *(const float4*)&cs[wr * 64 + mi * 32 + q * 8 + kh4];
                dmin = fminf(dmin, fmaf(-2.0f, acc[mi][nj][q * 4 + 0], cq.x));
                dmin = fminf(dmin, fmaf(-2.0f, acc[mi][nj][q * 4 + 1], cq.y));
                dmin = fminf(dmin, fmaf(-2.0f, acc[mi][nj][q * 4 + 2], cq.z));
                dmin = fminf(dmin, fmaf(-2.0f, acc[mi][nj][q * 4 + 3], cq.w));
            }
        }
        const int xr = wc * 64 + nj * 32 + (lane & 31);
        atomicMin(&smin[xr], __float_as_uint(dmin));
    }
    __syncthreads();
    if (tid < GBM) tmin[codetile * NROWS + row0 + tid] = smin[tid];
}

// ---------------- pass B: candidate tile selection ----------------
// Rigorous margin: 2E = 4.32e-5*sqrt(Z) (+ f32 tie window), round-6-validated.
__global__ __launch_bounds__(256) void k_select(
        const unsigned* __restrict__ tmin, const float* __restrict__ Z,
        int* __restrict__ cnt, int* __restrict__ list) {
    const int row = blockIdx.x * 256 + threadIdx.x;
    unsigned mn = 0xFFFFFFFFu;
    for (int t = 0; t < NTILE; ++t) {
        unsigned v = tmin[t * NROWS + row];
        if (v < mn) mn = v;
    }
    const float margin = 4.35e-5f * sqrtf(Z[row]) + 1.7e-4f;
    const float thr = __uint_as_float(mn) + margin;
    for (int t = 0; t < NTILE; ++t) {
        if (__uint_as_float(tmin[t * NROWS + row]) <= thr) {
            int p = atomicAdd(&cnt[t], 1);
            list[t * NROWS + p] = row;
        }
    }
}

// ---------------- pass C: exact 6-split MFMA rescore, SWAPPED -------------
// Same 6-block product order as rounds 5/8/9 (hi*HI last). Per lane: 32
// codes for one xrow -> per-lane (d,j) min (strict <, increasing j scan =
// first-index tiebreak), one packed-key global atomicMin per (lane,nj).
__global__ __launch_bounds__(256) void k_rescore_mfma(
        const unsigned short* __restrict__ Xe, const unsigned short* __restrict__ We,
        const float* __restrict__ Z, const float* __restrict__ c2,
        const int* __restrict__ cnt, const int* __restrict__ list,
        unsigned long long* __restrict__ keys) {
    __shared__ __align__(16) unsigned short At[GBM * GBK];
    __shared__ __align__(16) unsigned short Bt[GBN * GBK];
    __shared__ int rl_s[GBM];
    __shared__ float Zs[GBM];
    __shared__ float cs2[GBN];

    const int tile = blockIdx.x;
    const int n = cnt[tile];
    if (n == 0) return;
    const int* rows = list + tile * NROWS;
    const int tid = threadIdx.x;
    const int lane = tid & 63, wid = tid >> 6;
    const int wr = wid >> 1, wc = wid & 1;
    const int code0 = tile * 128;

    if (tid < GBN) cs2[tid] = c2[code0 + tid];

    const int cb0 = wr * 64 + (lane & 31);
    const int xa0 = wc * 64 + (lane & 31);
    const int kh  = lane >> 5;
    const int kh4 = kh * 4;
    const int sb  = cb0 & 7, sa = xa0 & 7;

    for (int chk = (int)blockIdx.y; chk * GBM < n; chk += 16) {
        __syncthreads();   // previous iteration fully done before rl_s/LDS reuse
        if (tid < GBM) {
            int ri = chk * GBM + tid;
            int r = rows[ri < n ? ri : 0];
            rl_s[tid] = r;
            Zs[tid] = Z[r];
        }
        __syncthreads();

        size_t aoff[4], boff[4];
#pragma unroll
        for (int i = 0; i < 4; ++i) {
            int chunk = i * 256 + tid;
            int row   = chunk >> 3;
            int kcs   = (chunk & 7) ^ (row & 7);
            aoff[i] = (size_t)rl_s[row] * K3 + kcs * 8;
            boff[i] = (size_t)(code0 + row) * K3 + kcs * 8;
        }

        f32x16 acc[2][2];
#pragma unroll
        for (int i = 0; i < 2; ++i)
#pragma unroll
            for (int j = 0; j < 2; ++j)
#pragma unroll
                for (int r = 0; r < 16; ++r) acc[i][j][r] = 0.0f;

#pragma unroll
        for (int bt = 0; bt < 6; ++bt) {
            const int ao = (bt == 1 || bt == 2) ? EDIM : (bt == 4 ? 2 * EDIM : 0);
            const int bo = (bt == 0 || bt == 2) ? EDIM : (bt == 3 ? 2 * EDIM : 0);
            for (int kc = 0; kc < 8; ++kc) {
                const int ko = ao + kc * GBK;
                const int kob = bo + kc * GBK;
#pragma unroll
                for (int i = 0; i < 4; ++i) {
                    gld16(Xe + aoff[i] + ko,  (char*)At + i * 4096 + wid * 1024);
                    gld16(We + boff[i] + kob, (char*)Bt + i * 4096 + wid * 1024);
                }
                __syncthreads();
#pragma unroll
                for (int ks = 0; ks < 4; ++ks) {
                    const int ch = ks * 2 + kh;
                    short8 c0 = *(const short8*)((const char*)Bt + cb0 * 128        + ((ch ^ sb) * 16));
                    short8 c1 = *(const short8*)((const char*)Bt + (cb0 + 32) * 128 + ((ch ^ sb) * 16));
                    short8 x0 = *(const short8*)((const char*)At + xa0 * 128        + ((ch ^ sa) * 16));
                    short8 x1 = *(const short8*)((const char*)At + (xa0 + 32) * 128 + ((ch ^ sa) * 16));
                    acc[0][0] = __builtin_amdgcn_mfma_f32_32x32x16_bf16(c0, x0, acc[0][0], 0, 0, 0);
                    acc[0][1] = __builtin_amdgcn_mfma_f32_32x32x16_bf16(c0, x1, acc[0][1], 0, 0, 0);
                    acc[1][0] = __builtin_amdgcn_mfma_f32_32x32x16_bf16(c1, x0, acc[1][0], 0, 0, 0);
                    acc[1][1] = __builtin_amdgcn_mfma_f32_32x32x16_bf16(c1, x1, acc[1][1], 0, 0, 0);
                }
                __syncthreads();
            }
        }

        // epilogue: exact d = (Z + c2) - 2*m, per-lane (d,j) argmin
#pragma unroll
        for (int nj = 0; nj < 2; ++nj) {
            const int xr = wc * 64 + nj * 32 + (lane & 31);
            const float Zr = Zs[xr];
            float dm = 3.4e38f; int jm = 0;
#pragma unroll
            for (int mi = 0; mi < 2; ++mi) {
#pragma unroll
                for (int q = 0; q < 4; ++q) {
                    const float4 cq = *(const float4*)&cs2[wr * 64 + mi * 32 + q * 8 + kh4];
                    const int jb = code0 + wr * 64 + mi * 32 + q * 8 + kh4;
                    { const float d = (Zr + cq.x) - 2.0f * acc[mi][nj][q * 4 + 0];
                      if (d < dm) { dm = d; jm = jb + 0; } }
                    { const float d = (Zr + cq.y) - 2.0f * acc[mi][nj][q * 4 + 1];
                      if (d < dm) { dm = d; jm = jb + 1; } }
                    { const float d = (Zr + cq.z) - 2.0f * acc[mi][nj][q * 4 + 2];
                      if (d < dm) { dm = d; jm = jb + 2; } }
                    { const float d = (Zr + cq.w) - 2.0f * acc[mi][nj][q * 4 + 3];
                      if (d < dm) { dm = d; jm = jb + 3; } }
                }
            }
            const unsigned long long k =
                (((unsigned long long)__float_as_uint(dm)) << 13) | (unsigned)jm;
            atomicMin(&keys[rl_s[xr]], k);
        }
    }
}

// ---------------- gather / loss partials / finalize ----------------
__global__ __launch_bounds__(256) void k_gather(
        const float* __restrict__ x, const float* __restrict__ W,
        const unsigned long long* __restrict__ keys,
        float* __restrict__ out, double* __restrict__ part) {
    const int tid = threadIdx.x;
    const int row = blockIdx.x * 8 + (tid >> 5);
    const int c = tid & 31;
    const int idx = (int)(keys[row] & 0x1FFFull);

    const float* wrow = W + (size_t)idx * EDIM;
    const float* xrow = x + (size_t)row * EDIM;
    float* orow = out + (size_t)row * EDIM;

    double lsum = 0.0;
#pragma unroll
    for (int v = 0; v < 4; ++v) {
        const int d = c * 4 + v * 128;
        float4 xv = *(const float4*)(xrow + d);
        float4 wv = *(const float4*)(wrow + d);
        float t0 = wv.x - xv.x, t1 = wv.y - xv.y, t2 = wv.z - xv.z, t3 = wv.w - xv.w;
        float4 ov = { xv.x + t0, xv.y + t1, xv.z + t2, xv.w + t3 };
        *(float4*)(orow + d) = ov;
        lsum += (double)t0 * t0 + (double)t1 * t1 + (double)t2 * t2 + (double)t3 * t3;
    }
    if (c == 0) out[XQSZ + 1 + row] = (float)idx;

#pragma unroll
    for (int off = 32; off > 0; off >>= 1) lsum += __shfl_down(lsum, off, 64);
    __shared__ double pb[4];
    if ((tid & 63) == 0) pb[tid >> 6] = lsum;
    __syncthreads();
    if (tid == 0) part[blockIdx.x] = pb[0] + pb[1] + pb[2] + pb[3];
}

__global__ __launch_bounds__(256) void k_finalize(float* __restrict__ out,
        const double* __restrict__ part) {
    const int tid = threadIdx.x;
    double s = 0.0;
    for (int i = tid; i < 2048; i += 256) s += part[i];
#pragma unroll
    for (int off = 32; off > 0; off >>= 1) s += __shfl_down(s, off, 64);
    __shared__ double pb[4];
    if ((tid & 63) == 0) pb[tid >> 6] = s;
    __syncthreads();
    if (tid == 0) out[XQSZ] = (float)(0.25 * (pb[0] + pb[1] + pb[2] + pb[3]) / (double)XQSZ);
}

extern "C" void kernel_launch(void* const* d_in, const int* in_sizes, int n_in,
                              void* d_out, int out_size, void* d_ws, size_t ws_size,
                              hipStream_t stream) {
    const float* x = (const float*)d_in[0];
    const float* W = (const float*)d_in[3];
    float* out = (float*)d_out;
    char* ws = (char*)d_ws;

    double* part = (double*)(ws + OFF_PART);
    float* Z    = (float*)(ws + OFF_Z);
    float* c2   = (float*)(ws + OFF_C2);
    unsigned long long* keys = (unsigned long long*)(ws + OFF_KEYS);
    unsigned* tmin = (unsigned*)(ws + OFF_TMIN);
    int* cnt  = (int*)(ws + OFF_CNT);
    int* list = (int*)(ws + OFF_LIST);
    unsigned short* Xe = (unsigned short*)(ws + OFF_XE);
    unsigned short* We = (unsigned short*)(ws + OFF_WE);

    hipMemsetAsync(keys, 0xFF, NROWS * sizeof(unsigned long long), stream);
    hipMemsetAsync(cnt, 0, NTILE * sizeof(int), stream);
    k_rownorm<<<NROWS / 256, 256, 0, stream>>>(x, Z, NROWS);
    k_rownorm<<<NE / 256, 256, 0, stream>>>(W, c2, NE);
    k_split3<<<(NROWS * 128) / 256, 256, 0, stream>>>(x, Xe, NROWS);
    k_split3<<<(NE * 128) / 256, 256, 0, stream>>>(W, We, NE);
    k_argmin_hi<<<(NROWS / GBM) * (NE / GBN), 256, 0, stream>>>(Xe, We, c2, tmin);
    k_select<<<NROWS / 256, 256, 0, stream>>>(tmin, Z, cnt, list);
    k_rescore_mfma<<<dim3(NTILE, 16), 256, 0, stream>>>(Xe, We, Z, c2, cnt, list, keys);
    k_gather<<<NROWS / 8, 256, 0, stream>>>(x, W, keys, out, part);
    k_finalize<<<1, 256, 0, stream>>>(out, part);
}